// Round 9
// baseline (93.198 us; speedup 1.0000x reference)
//
#include <hip/hip_runtime.h>

typedef unsigned int  u32;
typedef unsigned short u16;

typedef float    f4  __attribute__((ext_vector_type(4)));
typedef short    bf8 __attribute__((ext_vector_type(8)));
typedef __fp16   h8  __attribute__((ext_vector_type(8)));
typedef __fp16   h2  __attribute__((ext_vector_type(2)));

#define NBLK  256    // 256 blocks * 16 waves * 64 boards = 262144 ; 1 block per CU
#define ZSTR  104    // z1 row stride (u16); 52 dw/row; 16B-aligned rows (b128)

// fp32 -> bf16 bits, round-half-up (weights only; ties are measure-zero)
__device__ __forceinline__ u32 bfr(float f) {
    union { float f; u32 u; } v; v.f = f;
    return (v.u + 0x8000u) >> 16;
}
__device__ __forceinline__ u32 pk2(float lo, float hi) { return bfr(lo) | (bfr(hi) << 16); }
__device__ __forceinline__ u32 pkh(float lo, float hi) {   // fp16 pair (RTZ, 1 inst)
    union { h2 h; u32 u; } v; v.h = __builtin_amdgcn_cvt_pkrtz(lo, hi); return v.u;
}
// packed fp16 relu: one v_pk_max_f16 against 0 (inline asm; ROCm 7.2 __hmax2 header is broken)
__device__ __forceinline__ u32 pkmax0(u32 x) {
    u32 r; asm("v_pk_max_f16 %0, %1, %2" : "=v"(r) : "v"(x), "v"(0u)); return r;
}
__device__ __forceinline__ u32 nrev(u32 x) {
    return ((x >> 12) & 0xFu) | ((x >> 4) & 0xF0u) | ((x << 4) & 0xF00u) | ((x << 12) & 0xF000u);
}
// compiler-level DS ordering fence: cross-lane LDS dataflow is invisible to per-lane alias
// analysis (R6 post-mortem: zb read hoisted above z1 writes -> read poison -> NaN).
__device__ __forceinline__ void ds_fence() {
    asm volatile("" ::: "memory");
    __builtin_amdgcn_sched_barrier(0);
}

// ---- phase 1: flips + z1 row build + fragment read-back, wave-private rows ----
__device__ __forceinline__ void phase1_fn(const int4 e4, u16* __restrict__ zrow,
                                          const uint2* __restrict__ Th, const uint2* __restrict__ Tv,
                                          const int m, const int qd,
                                          bf8& zb0, bf8& zb1, bf8& zb2, bool& fv, bool& fh)
{
    u32 pkd = (u32)e4.x | ((u32)e4.y << 4) | ((u32)e4.z << 8) | ((u32)e4.w << 12);
    u32 R0 = (u32)__shfl((int)pkd, m);
    u32 R1 = (u32)__shfl((int)pkd, m + 16);
    u32 R2 = (u32)__shfl((int)pkd, m + 32);
    u32 R3 = (u32)__shfl((int)pkd, m + 48);
    u32 c0v = R0 & 15u, c1v = (R0 >> 12) & 15u, c2v = R3 & 15u, c3v = (R3 >> 12) & 15u;
    u32 best = c0v; int ix = 0;
    if (c1v > best) { best = c1v; ix = 1; }
    if (c2v > best) { best = c2v; ix = 2; }
    if (c3v > best) { best = c3v; ix = 3; }
    fv = (ix >= 2); fh = ((ix & 1) != 0);
    u32 F0 = fv ? R3 : R0;
    u32 F1 = fv ? R2 : R1;
    u32 F2 = fv ? R1 : R2;
    u32 F3 = fv ? R0 : R3;
    if (fh) { F0 = nrev(F0); F1 = nrev(F1); F2 = nrev(F2); F3 = nrev(F3); }

    const u32 Fq = (qd == 0) ? F0 : (qd == 1) ? F1 : (qd == 2) ? F2 : F3;
    u32 nbq0 = Fq & 15u, nbq1 = (Fq >> 4) & 15u, nbq2 = (Fq >> 8) & 15u, nbq3 = (Fq >> 12) & 15u;
    u32 nbc0 = (F0 >> (4*qd)) & 15u, nbc1 = (F1 >> (4*qd)) & 15u;
    u32 nbc2 = (F2 >> (4*qd)) & 15u, nbc3 = (F3 >> (4*qd)) & 15u;

    uint2 H0 = Th[nbq0*11u + nbq1];
    uint2 H1 = Th[nbq1*11u + nbq2];
    uint2 H2 = Th[nbq2*11u + nbq3];
    uint2 V0 = Tv[nbc0*11u + nbc1];
    uint2 V1 = Tv[nbc1*11u + nbc2];
    uint2 V2 = Tv[nbc2*11u + nbc3];

    *(uint2*)(zrow + (qd*3 + 0)*4) = H0;
    *(uint2*)(zrow + (qd*3 + 1)*4) = H1;
    *(uint2*)(zrow + (qd*3 + 2)*4) = H2;
    *(uint2*)(zrow + 48 + (0*4 + qd)*4) = V0;
    *(uint2*)(zrow + 48 + (1*4 + qd)*4) = V1;
    *(uint2*)(zrow + 48 + (2*4 + qd)*4) = V2;

    ds_fence();   // RAW: all 64 lanes' writes issue before any lane's read-back

    zb0 = *(const bf8*)(zrow + qd*8);
    zb1 = *(const bf8*)(zrow + 32 + qd*8);
    zb2 = *(const bf8*)(zrow + 64 + qd*8);

    ds_fence();   // WAR: next call's writes must not hoist above these reads
}

// ======================= single fused kernel =======================
// R8 post-mortem: cross-round decomposition (R0/R3/R5 measured mains vs totals) shows the
// 2-kernel structure pays ~15us in prep dispatch + inter-dispatch gap, while main has been
// ~27us since R4. This round: fuse the weight transform back in-kernel at 1024-thread/CU
// granularity (3 b128-grouped af writes/thread, ~2-3us) and launch ONE kernel.
// Loop body byte-identical to R8 (single-variable test of the dispatch-overhead theory).
__launch_bounds__(1024, 4)
__global__ void smartcnn_fused(const int* __restrict__ exps,
                               const float* __restrict__ c0w, const float* __restrict__ c0b,
                               const float* __restrict__ c1w,
                               const float* __restrict__ lw,  const float* __restrict__ lb,
                               const float* __restrict__ ow,  const float* __restrict__ ob,
                               float* __restrict__ out)
{
    __shared__ u16   afL[48 * 512];      // 49152 B : all 48 W1 fragments (ONE copy per CU)
    __shared__ uint2 ThA[121];           // conv0 pair table
    __shared__ uint2 TvA[121];           // conv1 pair table
    __shared__ f4    lbL[64];            //  1024 B : [T*4+qd] -> linear_b frag (broadcast read)
    __shared__ u32   owL[2048];          //  8192 B : out_w frags [c*256 + lane*4 + k]
    __shared__ u16   z1[256 * ZSTR];     // 53248 B : 16 rows per wave x 16 waves

    const int tid  = threadIdx.x;
    const int w    = tid >> 6;           // wave id 0..15
    const int lane = tid & 63;
    const int m    = lane & 15;
    const int qd   = lane >> 4;

    // ---- in-block weight transform (was smartcnn_prep; amortized over 1024 boards) ----
    // conv pair tables: 242 threads compute one entry each
    if (tid < 242) {
        const int e = (tid < 121) ? tid : tid - 121;
        const int v1 = e / 11, v2 = e - v1*11;
        float a[4];
        #pragma unroll
        for (int c = 0; c < 4; ++c) {
            if (tid < 121)
                a[c] = fmaxf(c0w[c*24 + 0] + c0w[c*24 + (1+v1)*2 + 0] + c0b[c]
                           + c0w[c*24 + 1] + c0w[c*24 + (1+v2)*2 + 1], 0.f);
            else
                a[c] = fmaxf(c1w[c*24 + 0] + c1w[c*24 + (1+v1)*2 + 0]
                           + c1w[c*24 + 1] + c1w[c*24 + (1+v2)*2 + 1], 0.f);
        }
        uint2 v = make_uint2(pk2(a[0], a[1]), pk2(a[2], a[3]));
        if (tid < 121) ThA[tid] = v; else TvA[tid - 121] = v;
    }
    // linear_b frags
    if (tid < 64) {
        const int T = tid >> 2, q = tid & 3;
        const int tb = ((T & 1) ? 4 : 0) + (T >> 1) * 32;
        lbL[tid] = *(const f4*)(lb + tb + 8 * q);
    }
    // W1 -> af fragments: K+M-permuted bf16. 3072 groups of 8 consecutive u16 (= b128 write);
    // each thread does 3 groups. lw reads are scattered within a 96-float row (L2/L3-hot).
    #pragma unroll
    for (int k = 0; k < 3; ++k) {
        const int g    = k * 1024 + tid;     // 0..3071
        const int gl   = g & 63;             // lane slot within fragment
        const int rest = g >> 6;             // 0..47 = T*3 + s
        const int s    = rest % 3;
        const int wtt  = rest / 3;           // T = 0..15
        const int tt = wtt & 3, ww = wtt >> 2;
        const int tbase = ((tt & 1) ? 4 : 0) + ((tt >> 1) ? 32 : 0);
        const int gm = gl & 15, gq = gl >> 4;
        const int fid = 64*ww + tbase + 8*(gm >> 2) + (gm & 3);   // M-permuted feature row
        const int kp0 = s*32 + gq*8;                              // 8 consecutive kp (uniform side of 48)
        const int kb  = (kp0 < 48) ? 0 : 48;
        const float* lrow = lw + fid*96 + kb;
        union { u16 e[8]; uint4 v; } pk;
        #pragma unroll
        for (int j = 0; j < 8; ++j) {
            const int kq = kp0 + j - kb;
            const int ko = (kq & 3)*12 + (kq >> 2);               // invert K-permutation
            pk.e[j] = (u16)bfr(lrow[ko]);
        }
        *(uint4*)(&afL[g * 8]) = pk.v;
    }
    // out_w fp16-pair frags: 512 groups of 4 u32 (= b128 write), one per thread (tid<512)
    if (tid < 512) {
        const int gl = tid & 63, wc = tid >> 6;
        const int gm = gl & 15, gq = gl >> 4;
        const int cc = wc & 1, ww = wc >> 1;
        uint4 v = make_uint4(0u, 0u, 0u, 0u);
        if (gm < 4) {   // rows 0-3 = actions, rows 4-15 = 0
            const int n8 = 64*ww + 32*cc + gq*8;
            const float* orow = ow + gm*256 + n8;
            v.x = pkh(orow[0], orow[1]);
            v.y = pkh(orow[2], orow[3]);
            v.z = pkh(orow[4], orow[5]);
            v.w = pkh(orow[6], orow[7]);
        }
        *(uint4*)(&owL[tid * 4]) = v;
    }
    const float4 obv = *(const float4*)ob;
    u16* zrow = &z1[(w*16 + m) * ZSTR];

    __syncthreads();   // the ONLY barrier (setup publish)

    const int wbase = blockIdx.x * 1024 + w * 64;   // this wave's first board (64 boards/wave)
    int4 e4a = *(const int4*)(exps + (size_t)(wbase + m)*16 + qd*4);
    int4 e4b = *(const int4*)(exps + (size_t)(wbase + 16 + m)*16 + qd*4);

    #pragma unroll 1
    for (int si = 0; si < 2; ++si) {
        // ---- phase1 both groups (z1 rows reused same-wave; zb frags land in 24 VGPRs) ----
        bf8 za0, za1, za2, zc0, zc1, zc2;
        bool fva, fha, fvb, fhb;
        phase1_fn(e4a, zrow, &ThA[0], &TvA[0], m, qd, za0, za1, za2, fva, fha);
        phase1_fn(e4b, zrow, &ThA[0], &TvA[0], m, qd, zc0, zc1, zc2, fvb, fhb);

        // prefetch next pass's boards (in flight across the whole c-loop)
        const int sn = (si < 1) ? si + 1 : si;
        e4a = *(const int4*)(exps + (size_t)(wbase + sn*32 + m)*16 + qd*4);
        e4b = *(const int4*)(exps + (size_t)(wbase + sn*32 + 16 + m)*16 + qd*4);

        // ---- fused GEMM1+GEMM2 over 8 c-blocks (tile pair 2c,2c+1 -> fold into logits) ----
        f4 pa = {0.f,0.f,0.f,0.f}, pb = {0.f,0.f,0.f,0.f};
        __builtin_amdgcn_s_setprio(1);
        #pragma unroll 1        // runtime c keeps af loads from being hoisted (R3/R5 spill trap)
        for (int c = 0; c < 8; ++c) {
            const u16* ap = &afL[c*3072 + lane*8];
            bf8 a00 = *(const bf8*)(ap);
            bf8 a01 = *(const bf8*)(ap + 512);
            bf8 a02 = *(const bf8*)(ap + 1024);
            bf8 a10 = *(const bf8*)(ap + 1536);
            bf8 a11 = *(const bf8*)(ap + 2048);
            bf8 a12 = *(const bf8*)(ap + 2560);
            f4 lb0 = lbL[c*8 + qd];
            f4 lb1 = lbL[c*8 + 4 + qd];
            union { u32 u[4]; h8 v; } au;
            uint4 owt = *(const uint4*)(&owL[c*256 + lane*4]);
            au.u[0] = owt.x; au.u[1] = owt.y; au.u[2] = owt.z; au.u[3] = owt.w;

            // group a: 2 feature tiles (K=96) -> relu/fp16 pack -> GEMM2 fold
            f4 x0 = __builtin_amdgcn_mfma_f32_16x16x32_bf16(a00, za0, lb0, 0, 0, 0);
            x0     = __builtin_amdgcn_mfma_f32_16x16x32_bf16(a01, za1, x0, 0, 0, 0);
            x0     = __builtin_amdgcn_mfma_f32_16x16x32_bf16(a02, za2, x0, 0, 0, 0);
            f4 x1 = __builtin_amdgcn_mfma_f32_16x16x32_bf16(a10, za0, lb1, 0, 0, 0);
            x1     = __builtin_amdgcn_mfma_f32_16x16x32_bf16(a11, za1, x1, 0, 0, 0);
            x1     = __builtin_amdgcn_mfma_f32_16x16x32_bf16(a12, za2, x1, 0, 0, 0);
            union { u32 u[4]; h8 v; } bu;
            bu.u[0] = pkmax0(pkh(x0[0], x0[1]));
            bu.u[1] = pkmax0(pkh(x0[2], x0[3]));
            bu.u[2] = pkmax0(pkh(x1[0], x1[1]));
            bu.u[3] = pkmax0(pkh(x1[2], x1[3]));
            pa = __builtin_amdgcn_mfma_f32_16x16x32_f16(au.v, bu.v, pa, 0, 0, 0);

            // group b: reuses a*, lb*, au (32 boards per weight read)
            f4 y0 = __builtin_amdgcn_mfma_f32_16x16x32_bf16(a00, zc0, lb0, 0, 0, 0);
            y0     = __builtin_amdgcn_mfma_f32_16x16x32_bf16(a01, zc1, y0, 0, 0, 0);
            y0     = __builtin_amdgcn_mfma_f32_16x16x32_bf16(a02, zc2, y0, 0, 0, 0);
            f4 y1 = __builtin_amdgcn_mfma_f32_16x16x32_bf16(a10, zc0, lb1, 0, 0, 0);
            y1     = __builtin_amdgcn_mfma_f32_16x16x32_bf16(a11, zc1, y1, 0, 0, 0);
            y1     = __builtin_amdgcn_mfma_f32_16x16x32_bf16(a12, zc2, y1, 0, 0, 0);
            bu.u[0] = pkmax0(pkh(y0[0], y0[1]));
            bu.u[1] = pkmax0(pkh(y0[2], y0[3]));
            bu.u[2] = pkmax0(pkh(y1[0], y1[1]));
            bu.u[3] = pkmax0(pkh(y1[2], y1[3]));
            pb = __builtin_amdgcn_mfma_f32_16x16x32_f16(au.v, bu.v, pb, 0, 0, 0);
        }
        __builtin_amdgcn_s_setprio(0);

        // ---- epilogue: softmax + flip-permute + store (qd==0 lanes hold the 4 action rows) ----
        if (qd == 0) {
            {
                float L0 = pa[0] + obv.x, L1 = pa[1] + obv.y, L2 = pa[2] + obv.z, L3 = pa[3] + obv.w;
                float mx = fmaxf(fmaxf(L0, L1), fmaxf(L2, L3));
                float e0 = __expf(L0-mx), e1 = __expf(L1-mx), e2 = __expf(L2-mx), e3 = __expf(L3-mx);
                float inv = __builtin_amdgcn_rcpf(e0 + e1 + e2 + e3);
                float P0 = e0*inv, P1 = e1*inv, P2 = e2*inv, P3 = e3*inv;
                float4 o;
                o.x = fva ? P1 : P0;
                o.y = fva ? P0 : P1;
                o.z = fha ? P3 : P2;
                o.w = fha ? P2 : P3;
                *(float4*)(out + (size_t)(wbase + si*32 + m) * 4) = o;
            }
            {
                float L0 = pb[0] + obv.x, L1 = pb[1] + obv.y, L2 = pb[2] + obv.z, L3 = pb[3] + obv.w;
                float mx = fmaxf(fmaxf(L0, L1), fmaxf(L2, L3));
                float e0 = __expf(L0-mx), e1 = __expf(L1-mx), e2 = __expf(L2-mx), e3 = __expf(L3-mx);
                float inv = __builtin_amdgcn_rcpf(e0 + e1 + e2 + e3);
                float P0 = e0*inv, P1 = e1*inv, P2 = e2*inv, P3 = e3*inv;
                float4 o;
                o.x = fvb ? P1 : P0;
                o.y = fvb ? P0 : P1;
                o.z = fhb ? P3 : P2;
                o.w = fhb ? P2 : P3;
                *(float4*)(out + (size_t)(wbase + si*32 + 16 + m) * 4) = o;
            }
        }
    }
}

extern "C" void kernel_launch(void* const* d_in, const int* in_sizes, int n_in,
                              void* d_out, int out_size, void* d_ws, size_t ws_size,
                              hipStream_t stream) {
    const int*   exps = (const int*)  d_in[0];
    const float* c0w  = (const float*)d_in[1];
    const float* c0b  = (const float*)d_in[2];
    const float* c1w  = (const float*)d_in[3];
    const float* lw   = (const float*)d_in[4];
    const float* lbv  = (const float*)d_in[5];
    const float* oww  = (const float*)d_in[6];
    const float* obv  = (const float*)d_in[7];
    (void)d_ws; (void)ws_size;
    smartcnn_fused<<<NBLK, 1024, 0, stream>>>(exps, c0w, c0b, c1w, lw, lbv, oww, obv, (float*)d_out);
}

// Round 10
// 89.341 us; speedup vs baseline: 1.0432x; 1.0432x over previous
//
#include <hip/hip_runtime.h>

typedef unsigned int  u32;
typedef unsigned short u16;

typedef float    f4  __attribute__((ext_vector_type(4)));
typedef short    bf8 __attribute__((ext_vector_type(8)));
typedef __fp16   h8  __attribute__((ext_vector_type(8)));
typedef __fp16   h2  __attribute__((ext_vector_type(2)));

#define NBLK  256    // 256 blocks * 16 waves * 64 boards = 262144 ; 1 block per CU
#define ZSTR  104    // z1 row stride (u16); 52 dw/row; 16B-aligned rows (b128)

// fp32 -> bf16 bits, round-half-up (weights only; ties are measure-zero)
__device__ __forceinline__ u32 bfr(float f) {
    union { float f; u32 u; } v; v.f = f;
    return (v.u + 0x8000u) >> 16;
}
__device__ __forceinline__ u32 pk2(float lo, float hi) { return bfr(lo) | (bfr(hi) << 16); }
__device__ __forceinline__ u32 pkh(float lo, float hi) {   // fp16 pair (RTZ, 1 inst)
    union { h2 h; u32 u; } v; v.h = __builtin_amdgcn_cvt_pkrtz(lo, hi); return v.u;
}
// packed fp16 relu: one v_pk_max_f16 against 0 (inline asm; ROCm 7.2 __hmax2 header is broken)
__device__ __forceinline__ u32 pkmax0(u32 x) {
    u32 r; asm("v_pk_max_f16 %0, %1, %2" : "=v"(r) : "v"(x), "v"(0u)); return r;
}
__device__ __forceinline__ u32 nrev(u32 x) {
    return ((x >> 12) & 0xFu) | ((x >> 4) & 0xF0u) | ((x << 4) & 0xF00u) | ((x << 12) & 0xF000u);
}
// compiler-level DS ordering fence: cross-lane LDS dataflow is invisible to per-lane alias
// analysis (R6 post-mortem: zb read hoisted above z1 writes -> read poison -> NaN).
__device__ __forceinline__ void ds_fence() {
    asm volatile("" ::: "memory");
    __builtin_amdgcn_sched_barrier(0);
}

// ---- phase 1: flips + z1 row build + fragment read-back, wave-private rows ----
__device__ __forceinline__ void phase1_fn(const int4 e4, u16* __restrict__ zrow,
                                          const uint2* __restrict__ Th, const uint2* __restrict__ Tv,
                                          const int m, const int qd,
                                          bf8& zb0, bf8& zb1, bf8& zb2, bool& fv, bool& fh)
{
    u32 pkd = (u32)e4.x | ((u32)e4.y << 4) | ((u32)e4.z << 8) | ((u32)e4.w << 12);
    u32 R0 = (u32)__shfl((int)pkd, m);
    u32 R1 = (u32)__shfl((int)pkd, m + 16);
    u32 R2 = (u32)__shfl((int)pkd, m + 32);
    u32 R3 = (u32)__shfl((int)pkd, m + 48);
    u32 c0v = R0 & 15u, c1v = (R0 >> 12) & 15u, c2v = R3 & 15u, c3v = (R3 >> 12) & 15u;
    u32 best = c0v; int ix = 0;
    if (c1v > best) { best = c1v; ix = 1; }
    if (c2v > best) { best = c2v; ix = 2; }
    if (c3v > best) { best = c3v; ix = 3; }
    fv = (ix >= 2); fh = ((ix & 1) != 0);
    u32 F0 = fv ? R3 : R0;
    u32 F1 = fv ? R2 : R1;
    u32 F2 = fv ? R1 : R2;
    u32 F3 = fv ? R0 : R3;
    if (fh) { F0 = nrev(F0); F1 = nrev(F1); F2 = nrev(F2); F3 = nrev(F3); }

    const u32 Fq = (qd == 0) ? F0 : (qd == 1) ? F1 : (qd == 2) ? F2 : F3;
    u32 nbq0 = Fq & 15u, nbq1 = (Fq >> 4) & 15u, nbq2 = (Fq >> 8) & 15u, nbq3 = (Fq >> 12) & 15u;
    u32 nbc0 = (F0 >> (4*qd)) & 15u, nbc1 = (F1 >> (4*qd)) & 15u;
    u32 nbc2 = (F2 >> (4*qd)) & 15u, nbc3 = (F3 >> (4*qd)) & 15u;

    uint2 H0 = Th[nbq0*11u + nbq1];
    uint2 H1 = Th[nbq1*11u + nbq2];
    uint2 H2 = Th[nbq2*11u + nbq3];
    uint2 V0 = Tv[nbc0*11u + nbc1];
    uint2 V1 = Tv[nbc1*11u + nbc2];
    uint2 V2 = Tv[nbc2*11u + nbc3];

    *(uint2*)(zrow + (qd*3 + 0)*4) = H0;
    *(uint2*)(zrow + (qd*3 + 1)*4) = H1;
    *(uint2*)(zrow + (qd*3 + 2)*4) = H2;
    *(uint2*)(zrow + 48 + (0*4 + qd)*4) = V0;
    *(uint2*)(zrow + 48 + (1*4 + qd)*4) = V1;
    *(uint2*)(zrow + 48 + (2*4 + qd)*4) = V2;

    ds_fence();   // RAW: all 64 lanes' writes issue before any lane's read-back

    zb0 = *(const bf8*)(zrow + qd*8);
    zb1 = *(const bf8*)(zrow + 32 + qd*8);
    zb2 = *(const bf8*)(zrow + 64 + qd*8);

    ds_fence();   // WAR: next call's writes must not hoist above these reads
}

// ======================= single fused kernel =======================
// R9 post-mortem: single-kernel saves ~12us (launch ~10us/kernel + prep), but R9's af staging
// cost ~18us (24 scattered 4B global reads/thread = gather-heavy). This round: SOURCE-LINEAR
// staging — 6 perfectly-coalesced float4 reads of lw per thread, destination LDS index computed
// by the (verified-invertible) K/M-permutation, scattered via cheap ds_write_b16. Setup ~2us.
// Loop body byte-identical to R8/R9.
__launch_bounds__(1024, 4)
__global__ void smartcnn_fused(const int* __restrict__ exps,
                               const float* __restrict__ c0w, const float* __restrict__ c0b,
                               const float* __restrict__ c1w,
                               const float* __restrict__ lw,  const float* __restrict__ lb,
                               const float* __restrict__ ow,  const float* __restrict__ ob,
                               float* __restrict__ out)
{
    __shared__ u16   afL[48 * 512];      // 49152 B : all 48 W1 fragments (ONE copy per CU)
    __shared__ uint2 ThA[121];           // conv0 pair table
    __shared__ uint2 TvA[121];           // conv1 pair table
    __shared__ f4    lbL[64];            //  1024 B : [T*4+qd] -> linear_b frag (broadcast read)
    __shared__ u32   owL[2048];          //  8192 B : out_w frags [c*256 + lane*4 + k]
    __shared__ u16   z1[256 * ZSTR];     // 53248 B : 16 rows per wave x 16 waves

    const int tid  = threadIdx.x;
    const int w    = tid >> 6;           // wave id 0..15
    const int lane = tid & 63;
    const int m    = lane & 15;
    const int qd   = lane >> 4;

    // ---- in-block weight transform ----
    // conv pair tables: 242 threads compute one entry each (c0w/c1w are tiny, L2-hot)
    if (tid < 242) {
        const int e = (tid < 121) ? tid : tid - 121;
        const int v1 = e / 11, v2 = e - v1*11;
        float a[4];
        #pragma unroll
        for (int c = 0; c < 4; ++c) {
            if (tid < 121)
                a[c] = fmaxf(c0w[c*24 + 0] + c0w[c*24 + (1+v1)*2 + 0] + c0b[c]
                           + c0w[c*24 + 1] + c0w[c*24 + (1+v2)*2 + 1], 0.f);
            else
                a[c] = fmaxf(c1w[c*24 + 0] + c1w[c*24 + (1+v1)*2 + 0]
                           + c1w[c*24 + 1] + c1w[c*24 + (1+v2)*2 + 1], 0.f);
        }
        uint2 v = make_uint2(pk2(a[0], a[1]), pk2(a[2], a[3]));
        if (tid < 121) ThA[tid] = v; else TvA[tid - 121] = v;
    }
    // linear_b frags
    if (tid < 64) {
        const int T = tid >> 2, q = tid & 3;
        const int tb = ((T & 1) ? 4 : 0) + (T >> 1) * 32;
        lbL[tid] = *(const f4*)(lb + tb + 8 * q);
    }
    // W1 -> af fragments: source-linear COALESCED reads, permuted LDS scatter.
    // Forward map (prep): element (T,s,lane=(gq,gm),j) <- lw[fid*96+ko], fid=64w+tbase+8(gm>>2)+(gm&3),
    // kp=s*32+gq*8+j, ko=side+(kq&3)*12+(kq>>2). Inverse (verified round-trip):
    // kp = side + (kq%12)*4 + kq/12. Within one float4 (x%4==0): side uniform, no %12 wrap,
    // kp_e = kp0 + 4e.
    #pragma unroll
    for (int v = 0; v < 6; ++v) {
        const int x   = v * 4096 + tid * 4;          // source element index = fid*96 + ko
        const int fid = x / 96;                      // compile-time-const divisor -> magic mul
        const int ko0 = x - fid * 96;
        const int r   = fid & 63;
        const int T   = ((fid >> 6) << 2) | (((r >> 5) & 1) << 1) | ((r >> 2) & 1);
        const int gm  = (((r >> 3) & 3) << 2) | (r & 3);
        const int side = (ko0 >= 48) ? 48 : 0;
        const int kq0  = ko0 - side;
        const int kp0  = side + (kq0 % 12) * 4 + kq0 / 12;
        const int base = T * 1536 + gm * 8;
        const f4 fv4 = *(const f4*)(lw + x);         // 16B coalesced: lanes consecutive
        #pragma unroll
        for (int e = 0; e < 4; ++e) {
            const int kp  = kp0 + 4 * e;
            const int idx = base + ((kp >> 5) << 9) + (((kp >> 3) & 3) << 7) + (kp & 7);
            afL[idx] = (u16)bfr(fv4[e]);
        }
    }
    // out_w fp16-pair frags: 512 groups of 4 u32 (= b128 write), one per thread (tid<512)
    if (tid < 512) {
        const int gl = tid & 63, wc = tid >> 6;
        const int gm = gl & 15, gq = gl >> 4;
        const int cc = wc & 1, ww = wc >> 1;
        uint4 v = make_uint4(0u, 0u, 0u, 0u);
        if (gm < 4) {   // rows 0-3 = actions, rows 4-15 = 0
            const int n8 = 64*ww + 32*cc + gq*8;
            const float* orow = ow + gm*256 + n8;
            v.x = pkh(orow[0], orow[1]);
            v.y = pkh(orow[2], orow[3]);
            v.z = pkh(orow[4], orow[5]);
            v.w = pkh(orow[6], orow[7]);
        }
        *(uint4*)(&owL[tid * 4]) = v;
    }
    const float4 obv = *(const float4*)ob;
    u16* zrow = &z1[(w*16 + m) * ZSTR];

    __syncthreads();   // the ONLY barrier (setup publish)

    const int wbase = blockIdx.x * 1024 + w * 64;   // this wave's first board (64 boards/wave)
    int4 e4a = *(const int4*)(exps + (size_t)(wbase + m)*16 + qd*4);
    int4 e4b = *(const int4*)(exps + (size_t)(wbase + 16 + m)*16 + qd*4);

    #pragma unroll 1
    for (int si = 0; si < 2; ++si) {
        // ---- phase1 both groups (z1 rows reused same-wave; zb frags land in 24 VGPRs) ----
        bf8 za0, za1, za2, zc0, zc1, zc2;
        bool fva, fha, fvb, fhb;
        phase1_fn(e4a, zrow, &ThA[0], &TvA[0], m, qd, za0, za1, za2, fva, fha);
        phase1_fn(e4b, zrow, &ThA[0], &TvA[0], m, qd, zc0, zc1, zc2, fvb, fhb);

        // prefetch next pass's boards (in flight across the whole c-loop)
        const int sn = (si < 1) ? si + 1 : si;
        e4a = *(const int4*)(exps + (size_t)(wbase + sn*32 + m)*16 + qd*4);
        e4b = *(const int4*)(exps + (size_t)(wbase + sn*32 + 16 + m)*16 + qd*4);

        // ---- fused GEMM1+GEMM2 over 8 c-blocks (tile pair 2c,2c+1 -> fold into logits) ----
        f4 pa = {0.f,0.f,0.f,0.f}, pb = {0.f,0.f,0.f,0.f};
        __builtin_amdgcn_s_setprio(1);
        #pragma unroll 1        // runtime c keeps af loads from being hoisted (R3/R5 spill trap)
        for (int c = 0; c < 8; ++c) {
            const u16* ap = &afL[c*3072 + lane*8];
            bf8 a00 = *(const bf8*)(ap);
            bf8 a01 = *(const bf8*)(ap + 512);
            bf8 a02 = *(const bf8*)(ap + 1024);
            bf8 a10 = *(const bf8*)(ap + 1536);
            bf8 a11 = *(const bf8*)(ap + 2048);
            bf8 a12 = *(const bf8*)(ap + 2560);
            f4 lb0 = lbL[c*8 + qd];
            f4 lb1 = lbL[c*8 + 4 + qd];
            union { u32 u[4]; h8 v; } au;
            uint4 owt = *(const uint4*)(&owL[c*256 + lane*4]);
            au.u[0] = owt.x; au.u[1] = owt.y; au.u[2] = owt.z; au.u[3] = owt.w;

            // group a: 2 feature tiles (K=96) -> relu/fp16 pack -> GEMM2 fold
            f4 x0 = __builtin_amdgcn_mfma_f32_16x16x32_bf16(a00, za0, lb0, 0, 0, 0);
            x0     = __builtin_amdgcn_mfma_f32_16x16x32_bf16(a01, za1, x0, 0, 0, 0);
            x0     = __builtin_amdgcn_mfma_f32_16x16x32_bf16(a02, za2, x0, 0, 0, 0);
            f4 x1 = __builtin_amdgcn_mfma_f32_16x16x32_bf16(a10, za0, lb1, 0, 0, 0);
            x1     = __builtin_amdgcn_mfma_f32_16x16x32_bf16(a11, za1, x1, 0, 0, 0);
            x1     = __builtin_amdgcn_mfma_f32_16x16x32_bf16(a12, za2, x1, 0, 0, 0);
            union { u32 u[4]; h8 v; } bu;
            bu.u[0] = pkmax0(pkh(x0[0], x0[1]));
            bu.u[1] = pkmax0(pkh(x0[2], x0[3]));
            bu.u[2] = pkmax0(pkh(x1[0], x1[1]));
            bu.u[3] = pkmax0(pkh(x1[2], x1[3]));
            pa = __builtin_amdgcn_mfma_f32_16x16x32_f16(au.v, bu.v, pa, 0, 0, 0);

            // group b: reuses a*, lb*, au (32 boards per weight read)
            f4 y0 = __builtin_amdgcn_mfma_f32_16x16x32_bf16(a00, zc0, lb0, 0, 0, 0);
            y0     = __builtin_amdgcn_mfma_f32_16x16x32_bf16(a01, zc1, y0, 0, 0, 0);
            y0     = __builtin_amdgcn_mfma_f32_16x16x32_bf16(a02, zc2, y0, 0, 0, 0);
            f4 y1 = __builtin_amdgcn_mfma_f32_16x16x32_bf16(a10, zc0, lb1, 0, 0, 0);
            y1     = __builtin_amdgcn_mfma_f32_16x16x32_bf16(a11, zc1, y1, 0, 0, 0);
            y1     = __builtin_amdgcn_mfma_f32_16x16x32_bf16(a12, zc2, y1, 0, 0, 0);
            bu.u[0] = pkmax0(pkh(y0[0], y0[1]));
            bu.u[1] = pkmax0(pkh(y0[2], y0[3]));
            bu.u[2] = pkmax0(pkh(y1[0], y1[1]));
            bu.u[3] = pkmax0(pkh(y1[2], y1[3]));
            pb = __builtin_amdgcn_mfma_f32_16x16x32_f16(au.v, bu.v, pb, 0, 0, 0);
        }
        __builtin_amdgcn_s_setprio(0);

        // ---- epilogue: softmax + flip-permute + store (qd==0 lanes hold the 4 action rows) ----
        if (qd == 0) {
            {
                float L0 = pa[0] + obv.x, L1 = pa[1] + obv.y, L2 = pa[2] + obv.z, L3 = pa[3] + obv.w;
                float mx = fmaxf(fmaxf(L0, L1), fmaxf(L2, L3));
                float e0 = __expf(L0-mx), e1 = __expf(L1-mx), e2 = __expf(L2-mx), e3 = __expf(L3-mx);
                float inv = __builtin_amdgcn_rcpf(e0 + e1 + e2 + e3);
                float P0 = e0*inv, P1 = e1*inv, P2 = e2*inv, P3 = e3*inv;
                float4 o;
                o.x = fva ? P1 : P0;
                o.y = fva ? P0 : P1;
                o.z = fha ? P3 : P2;
                o.w = fha ? P2 : P3;
                *(float4*)(out + (size_t)(wbase + si*32 + m) * 4) = o;
            }
            {
                float L0 = pb[0] + obv.x, L1 = pb[1] + obv.y, L2 = pb[2] + obv.z, L3 = pb[3] + obv.w;
                float mx = fmaxf(fmaxf(L0, L1), fmaxf(L2, L3));
                float e0 = __expf(L0-mx), e1 = __expf(L1-mx), e2 = __expf(L2-mx), e3 = __expf(L3-mx);
                float inv = __builtin_amdgcn_rcpf(e0 + e1 + e2 + e3);
                float P0 = e0*inv, P1 = e1*inv, P2 = e2*inv, P3 = e3*inv;
                float4 o;
                o.x = fvb ? P1 : P0;
                o.y = fvb ? P0 : P1;
                o.z = fhb ? P3 : P2;
                o.w = fhb ? P2 : P3;
                *(float4*)(out + (size_t)(wbase + si*32 + 16 + m) * 4) = o;
            }
        }
    }
}

extern "C" void kernel_launch(void* const* d_in, const int* in_sizes, int n_in,
                              void* d_out, int out_size, void* d_ws, size_t ws_size,
                              hipStream_t stream) {
    const int*   exps = (const int*)  d_in[0];
    const float* c0w  = (const float*)d_in[1];
    const float* c0b  = (const float*)d_in[2];
    const float* c1w  = (const float*)d_in[3];
    const float* lw   = (const float*)d_in[4];
    const float* lbv  = (const float*)d_in[5];
    const float* oww  = (const float*)d_in[6];
    const float* obv  = (const float*)d_in[7];
    (void)d_ws; (void)ws_size;
    smartcnn_fused<<<NBLK, 1024, 0, stream>>>(exps, c0w, c0b, c1w, lw, lbv, oww, obv, (float*)d_out);
}

// Round 11
// 88.947 us; speedup vs baseline: 1.0478x; 1.0044x over previous
//
#include <hip/hip_runtime.h>

typedef unsigned int  u32;
typedef unsigned short u16;

typedef float    f4  __attribute__((ext_vector_type(4)));
typedef short    bf8 __attribute__((ext_vector_type(8)));
typedef __fp16   h8  __attribute__((ext_vector_type(8)));
typedef __fp16   h2  __attribute__((ext_vector_type(2)));

#define NBLK  256    // 256 blocks * 16 waves * 64 boards = 262144 ; 1 block per CU
#define ZSTR  104    // z1 row stride (u16); 52 dw/row; 16B-aligned rows (b128)

// fp32 -> bf16 bits, round-half-up (weights only; ties are measure-zero)
__device__ __forceinline__ u32 bfr(float f) {
    union { float f; u32 u; } v; v.f = f;
    return (v.u + 0x8000u) >> 16;
}
__device__ __forceinline__ u32 pk2(float lo, float hi) { return bfr(lo) | (bfr(hi) << 16); }
__device__ __forceinline__ u32 pkh(float lo, float hi) {   // fp16 pair (RTZ, 1 inst)
    union { h2 h; u32 u; } v; v.h = __builtin_amdgcn_cvt_pkrtz(lo, hi); return v.u;
}
// packed fp16 relu: one v_pk_max_f16 against 0 (inline asm; ROCm 7.2 __hmax2 header is broken)
__device__ __forceinline__ u32 pkmax0(u32 x) {
    u32 r; asm("v_pk_max_f16 %0, %1, %2" : "=v"(r) : "v"(x), "v"(0u)); return r;
}
__device__ __forceinline__ u32 nrev(u32 x) {
    return ((x >> 12) & 0xFu) | ((x >> 4) & 0xF0u) | ((x << 4) & 0xF00u) | ((x << 12) & 0xF000u);
}
// compiler-level DS ordering fence: cross-lane LDS dataflow is invisible to per-lane alias
// analysis (R6 post-mortem: zb read hoisted above z1 writes -> read poison -> NaN).
__device__ __forceinline__ void ds_fence() {
    asm volatile("" ::: "memory");
    __builtin_amdgcn_sched_barrier(0);
}

// ---- phase 1: flips + z1 row build + fragment read-back, wave-private rows ----
__device__ __forceinline__ void phase1_fn(const int4 e4, u16* __restrict__ zrow,
                                          const uint2* __restrict__ Th, const uint2* __restrict__ Tv,
                                          const int m, const int qd,
                                          bf8& zb0, bf8& zb1, bf8& zb2, bool& fv, bool& fh)
{
    u32 pkd = (u32)e4.x | ((u32)e4.y << 4) | ((u32)e4.z << 8) | ((u32)e4.w << 12);
    u32 R0 = (u32)__shfl((int)pkd, m);
    u32 R1 = (u32)__shfl((int)pkd, m + 16);
    u32 R2 = (u32)__shfl((int)pkd, m + 32);
    u32 R3 = (u32)__shfl((int)pkd, m + 48);
    u32 c0v = R0 & 15u, c1v = (R0 >> 12) & 15u, c2v = R3 & 15u, c3v = (R3 >> 12) & 15u;
    u32 best = c0v; int ix = 0;
    if (c1v > best) { best = c1v; ix = 1; }
    if (c2v > best) { best = c2v; ix = 2; }
    if (c3v > best) { best = c3v; ix = 3; }
    fv = (ix >= 2); fh = ((ix & 1) != 0);
    u32 F0 = fv ? R3 : R0;
    u32 F1 = fv ? R2 : R1;
    u32 F2 = fv ? R1 : R2;
    u32 F3 = fv ? R0 : R3;
    if (fh) { F0 = nrev(F0); F1 = nrev(F1); F2 = nrev(F2); F3 = nrev(F3); }

    const u32 Fq = (qd == 0) ? F0 : (qd == 1) ? F1 : (qd == 2) ? F2 : F3;
    u32 nbq0 = Fq & 15u, nbq1 = (Fq >> 4) & 15u, nbq2 = (Fq >> 8) & 15u, nbq3 = (Fq >> 12) & 15u;
    u32 nbc0 = (F0 >> (4*qd)) & 15u, nbc1 = (F1 >> (4*qd)) & 15u;
    u32 nbc2 = (F2 >> (4*qd)) & 15u, nbc3 = (F3 >> (4*qd)) & 15u;

    uint2 H0 = Th[nbq0*11u + nbq1];
    uint2 H1 = Th[nbq1*11u + nbq2];
    uint2 H2 = Th[nbq2*11u + nbq3];
    uint2 V0 = Tv[nbc0*11u + nbc1];
    uint2 V1 = Tv[nbc1*11u + nbc2];
    uint2 V2 = Tv[nbc2*11u + nbc3];

    *(uint2*)(zrow + (qd*3 + 0)*4) = H0;
    *(uint2*)(zrow + (qd*3 + 1)*4) = H1;
    *(uint2*)(zrow + (qd*3 + 2)*4) = H2;
    *(uint2*)(zrow + 48 + (0*4 + qd)*4) = V0;
    *(uint2*)(zrow + 48 + (1*4 + qd)*4) = V1;
    *(uint2*)(zrow + 48 + (2*4 + qd)*4) = V2;

    ds_fence();   // RAW: all 64 lanes' writes issue before any lane's read-back

    zb0 = *(const bf8*)(zrow + qd*8);
    zb1 = *(const bf8*)(zrow + 32 + qd*8);
    zb2 = *(const bf8*)(zrow + 64 + qd*8);

    ds_fence();   // WAR: next call's writes must not hoist above these reads
}

// ======================= single fused kernel, single-pass 4-group c-loop =======================
// R10 post-mortem: main ~40us across 3 structures, latency/queue-bound on the shared LDS pipe
// (issue floor ~16us/CU); the si-loop re-read all af/ow/lb weight fragments per pass. This round:
// ONE pass of FOUR board-groups -> each weight b128 feeds 64 boards. LDS b128/wave: 156 -> 84.
// Register audit: persistent zb 48 + p 16 + obv 4 + addr ~7 = 76 (bools -> SGPR masks);
// transient af 24 + au 4 + lb 8 + x 8 + bu 4 = 48; peak ~124 < 128 cap. Loop body ops identical.
__launch_bounds__(1024, 4)
__global__ void smartcnn_fused(const int* __restrict__ exps,
                               const float* __restrict__ c0w, const float* __restrict__ c0b,
                               const float* __restrict__ c1w,
                               const float* __restrict__ lw,  const float* __restrict__ lb,
                               const float* __restrict__ ow,  const float* __restrict__ ob,
                               float* __restrict__ out)
{
    __shared__ u16   afL[48 * 512];      // 49152 B : all 48 W1 fragments (ONE copy per CU)
    __shared__ uint2 ThA[121];           // conv0 pair table
    __shared__ uint2 TvA[121];           // conv1 pair table
    __shared__ f4    lbL[64];            //  1024 B : [T*4+qd] -> linear_b frag (broadcast read)
    __shared__ u32   owL[2048];          //  8192 B : out_w frags [c*256 + lane*4 + k]
    __shared__ u16   z1[256 * ZSTR];     // 53248 B : 16 rows per wave x 16 waves

    const int tid  = threadIdx.x;
    const int w    = tid >> 6;           // wave id 0..15
    const int lane = tid & 63;
    const int m    = lane & 15;
    const int qd   = lane >> 4;

    // ---- in-block weight transform (R10's source-linear staging, unchanged) ----
    if (tid < 242) {
        const int e = (tid < 121) ? tid : tid - 121;
        const int v1 = e / 11, v2 = e - v1*11;
        float a[4];
        #pragma unroll
        for (int c = 0; c < 4; ++c) {
            if (tid < 121)
                a[c] = fmaxf(c0w[c*24 + 0] + c0w[c*24 + (1+v1)*2 + 0] + c0b[c]
                           + c0w[c*24 + 1] + c0w[c*24 + (1+v2)*2 + 1], 0.f);
            else
                a[c] = fmaxf(c1w[c*24 + 0] + c1w[c*24 + (1+v1)*2 + 0]
                           + c1w[c*24 + 1] + c1w[c*24 + (1+v2)*2 + 1], 0.f);
        }
        uint2 v = make_uint2(pk2(a[0], a[1]), pk2(a[2], a[3]));
        if (tid < 121) ThA[tid] = v; else TvA[tid - 121] = v;
    }
    if (tid < 64) {
        const int T = tid >> 2, q = tid & 3;
        const int tb = ((T & 1) ? 4 : 0) + (T >> 1) * 32;
        lbL[tid] = *(const f4*)(lb + tb + 8 * q);
    }
    // W1 -> af fragments: source-linear coalesced float4 reads, permuted ds_write_b16 scatter.
    #pragma unroll
    for (int v = 0; v < 6; ++v) {
        const int x   = v * 4096 + tid * 4;          // source element index = fid*96 + ko
        const int fid = x / 96;                      // const divisor -> magic mul
        const int ko0 = x - fid * 96;
        const int r   = fid & 63;
        const int T   = ((fid >> 6) << 2) | (((r >> 5) & 1) << 1) | ((r >> 2) & 1);
        const int gm  = (((r >> 3) & 3) << 2) | (r & 3);
        const int side = (ko0 >= 48) ? 48 : 0;
        const int kq0  = ko0 - side;
        const int kp0  = side + (kq0 % 12) * 4 + kq0 / 12;
        const int base = T * 1536 + gm * 8;
        const f4 fv4 = *(const f4*)(lw + x);         // 16B coalesced
        #pragma unroll
        for (int e = 0; e < 4; ++e) {
            const int kp  = kp0 + 4 * e;
            const int idx = base + ((kp >> 5) << 9) + (((kp >> 3) & 3) << 7) + (kp & 7);
            afL[idx] = (u16)bfr(fv4[e]);
        }
    }
    if (tid < 512) {
        const int gl = tid & 63, wc = tid >> 6;
        const int gm = gl & 15, gq = gl >> 4;
        const int cc = wc & 1, ww = wc >> 1;
        uint4 v = make_uint4(0u, 0u, 0u, 0u);
        if (gm < 4) {   // rows 0-3 = actions, rows 4-15 = 0
            const int n8 = 64*ww + 32*cc + gq*8;
            const float* orow = ow + gm*256 + n8;
            v.x = pkh(orow[0], orow[1]);
            v.y = pkh(orow[2], orow[3]);
            v.z = pkh(orow[4], orow[5]);
            v.w = pkh(orow[6], orow[7]);
        }
        *(uint4*)(&owL[tid * 4]) = v;
    }
    const float4 obv = *(const float4*)ob;
    u16* zrow = &z1[(w*16 + m) * ZSTR];

    __syncthreads();   // the ONLY barrier (setup publish)

    const int wbase = blockIdx.x * 1024 + w * 64;   // this wave's first board (64 boards/wave)

    // ---- phase1 all four groups (zrow reused sequentially; fence pattern as proven x2) ----
    bf8 za0, za1, za2, zb0_, zb1_, zb2_, zc0, zc1, zc2, zd0, zd1, zd2;
    bool fva, fha, fvb, fhb, fvc, fhc, fvd, fhd;
    {
        int4 e4 = *(const int4*)(exps + (size_t)(wbase + m)*16 + qd*4);
        phase1_fn(e4, zrow, &ThA[0], &TvA[0], m, qd, za0, za1, za2, fva, fha);
    }
    {
        int4 e4 = *(const int4*)(exps + (size_t)(wbase + 16 + m)*16 + qd*4);
        phase1_fn(e4, zrow, &ThA[0], &TvA[0], m, qd, zb0_, zb1_, zb2_, fvb, fhb);
    }
    {
        int4 e4 = *(const int4*)(exps + (size_t)(wbase + 32 + m)*16 + qd*4);
        phase1_fn(e4, zrow, &ThA[0], &TvA[0], m, qd, zc0, zc1, zc2, fvc, fhc);
    }
    {
        int4 e4 = *(const int4*)(exps + (size_t)(wbase + 48 + m)*16 + qd*4);
        phase1_fn(e4, zrow, &ThA[0], &TvA[0], m, qd, zd0, zd1, zd2, fvd, fhd);
    }

    // ---- fused GEMM1+GEMM2, single pass: each weight read feeds 4 groups (64 boards) ----
    f4 pa = {0.f,0.f,0.f,0.f}, pb = {0.f,0.f,0.f,0.f};
    f4 pc = {0.f,0.f,0.f,0.f}, pd = {0.f,0.f,0.f,0.f};
    __builtin_amdgcn_s_setprio(1);
    #pragma unroll 1        // runtime c keeps af loads from being hoisted (R3/R5 spill trap)
    for (int c = 0; c < 8; ++c) {
        const u16* ap = &afL[c*3072 + lane*8];
        bf8 a00 = *(const bf8*)(ap);
        bf8 a01 = *(const bf8*)(ap + 512);
        bf8 a02 = *(const bf8*)(ap + 1024);
        bf8 a10 = *(const bf8*)(ap + 1536);
        bf8 a11 = *(const bf8*)(ap + 2048);
        bf8 a12 = *(const bf8*)(ap + 2560);
        f4 lb0 = lbL[c*8 + qd];
        f4 lb1 = lbL[c*8 + 4 + qd];
        union { u32 u[4]; h8 v; } au;
        uint4 owt = *(const uint4*)(&owL[c*256 + lane*4]);
        au.u[0] = owt.x; au.u[1] = owt.y; au.u[2] = owt.z; au.u[3] = owt.w;

        // per-group: 2 feature tiles (K=96) -> relu/fp16 pack -> GEMM2 fold (x/bu reused)
        #define GRP(Z0, Z1, Z2, PG)                                                        \
        {                                                                                  \
            f4 x0 = __builtin_amdgcn_mfma_f32_16x16x32_bf16(a00, Z0, lb0, 0, 0, 0);        \
            x0     = __builtin_amdgcn_mfma_f32_16x16x32_bf16(a01, Z1, x0, 0, 0, 0);        \
            x0     = __builtin_amdgcn_mfma_f32_16x16x32_bf16(a02, Z2, x0, 0, 0, 0);        \
            f4 x1 = __builtin_amdgcn_mfma_f32_16x16x32_bf16(a10, Z0, lb1, 0, 0, 0);        \
            x1     = __builtin_amdgcn_mfma_f32_16x16x32_bf16(a11, Z1, x1, 0, 0, 0);        \
            x1     = __builtin_amdgcn_mfma_f32_16x16x32_bf16(a12, Z2, x1, 0, 0, 0);        \
            union { u32 u[4]; h8 v; } bu;                                                  \
            bu.u[0] = pkmax0(pkh(x0[0], x0[1]));                                           \
            bu.u[1] = pkmax0(pkh(x0[2], x0[3]));                                           \
            bu.u[2] = pkmax0(pkh(x1[0], x1[1]));                                           \
            bu.u[3] = pkmax0(pkh(x1[2], x1[3]));                                           \
            PG = __builtin_amdgcn_mfma_f32_16x16x32_f16(au.v, bu.v, PG, 0, 0, 0);          \
        }
        GRP(za0,  za1,  za2,  pa)
        GRP(zb0_, zb1_, zb2_, pb)
        GRP(zc0,  zc1,  zc2,  pc)
        GRP(zd0,  zd1,  zd2,  pd)
        #undef GRP
    }
    __builtin_amdgcn_s_setprio(0);

    // ---- epilogue: softmax + flip-permute + store (qd==0 lanes hold the 4 action rows) ----
    if (qd == 0) {
        #define EPI(PG, FV, FH, G)                                                         \
        {                                                                                  \
            float L0 = PG[0] + obv.x, L1 = PG[1] + obv.y;                                  \
            float L2 = PG[2] + obv.z, L3 = PG[3] + obv.w;                                  \
            float mx = fmaxf(fmaxf(L0, L1), fmaxf(L2, L3));                                \
            float e0 = __expf(L0-mx), e1 = __expf(L1-mx);                                  \
            float e2 = __expf(L2-mx), e3 = __expf(L3-mx);                                  \
            float inv = __builtin_amdgcn_rcpf(e0 + e1 + e2 + e3);                          \
            float P0 = e0*inv, P1 = e1*inv, P2 = e2*inv, P3 = e3*inv;                      \
            float4 o;                                                                      \
            o.x = (FV) ? P1 : P0;                                                          \
            o.y = (FV) ? P0 : P1;                                                          \
            o.z = (FH) ? P3 : P2;                                                          \
            o.w = (FH) ? P2 : P3;                                                          \
            *(float4*)(out + (size_t)(wbase + (G)*16 + m) * 4) = o;                        \
        }
        EPI(pa, fva, fha, 0)
        EPI(pb, fvb, fhb, 1)
        EPI(pc, fvc, fhc, 2)
        EPI(pd, fvd, fhd, 3)
        #undef EPI
    }
}

extern "C" void kernel_launch(void* const* d_in, const int* in_sizes, int n_in,
                              void* d_out, int out_size, void* d_ws, size_t ws_size,
                              hipStream_t stream) {
    const int*   exps = (const int*)  d_in[0];
    const float* c0w  = (const float*)d_in[1];
    const float* c0b  = (const float*)d_in[2];
    const float* c1w  = (const float*)d_in[3];
    const float* lw   = (const float*)d_in[4];
    const float* lbv  = (const float*)d_in[5];
    const float* oww  = (const float*)d_in[6];
    const float* obv  = (const float*)d_in[7];
    (void)d_ws; (void)ws_size;
    smartcnn_fused<<<NBLK, 1024, 0, stream>>>(exps, c0w, c0b, c1w, lw, lbv, oww, obv, (float*)d_out);
}